// Round 3
// baseline (30092.236 us; speedup 1.0000x reference)
//
#include <hip/hip_runtime.h>
#include <hip/hip_bf16.h>

// xLSTMStack: proj -> 4x( LN -> conv-mix -> bf16 MFMA GEMM (xg) -> cooperative GRU scan + residual )
// Workspace layout (~134.2 MiB):
//   [0,96M)     xg bf16 [B*L*3H]   (first 64 MiB aliased as ln fp32, consumed before xg written)
//   [96,128M)   mixbf bf16 [B*L*H] (GEMM A input + residual source for GRU)
//   [128,134M)  Wih bf16 [4*3H*H]
//   [134M,+128K) hst u64 [2][B][H] tagged (value,step) h-state
// d_out (fp32 [B,L,H]) doubles as the inter-layer h buffer.

#define B_   16
#define L_   2048
#define IN_  64
#define H_   512
#define H3_  1536
#define NL_  4

typedef unsigned short u16;
typedef unsigned long long u64;
typedef short bf16x8 __attribute__((ext_vector_type(8)));
typedef float f32x4 __attribute__((ext_vector_type(4)));

__device__ __forceinline__ u16 f2bf(float f) {
  unsigned u = __float_as_uint(f);
  u = u + 0x7fffu + ((u >> 16) & 1u);
  return (u16)(u >> 16);
}
__device__ __forceinline__ float bf2f(u16 v) {
  return __uint_as_float(((unsigned)v) << 16);
}
__device__ __forceinline__ float gelu_exact(float x) {
  return 0.5f * x * (1.f + erff(x * 0.70710678118654752440f));
}
// fast sigmoid: exp(-x) saturates safely (inf -> rcp(inf)=0, 0 -> 1)
__device__ __forceinline__ float fast_sig(float x) {
  float e = __expf(-x);
  return __builtin_amdgcn_rcpf(1.f + e);
}
// fast tanh: clamp to +/-15 so e^{2x} can't overflow into inf/inf
__device__ __forceinline__ float fast_tanh(float x) {
  x = fminf(fmaxf(x, -15.f), 15.f);
  float e = __expf(2.f * x);
  return (e - 1.f) * __builtin_amdgcn_rcpf(e + 1.f);
}

// ---------------- init: zero tagged h-state ----------------
__global__ void k_init(u64* hst, int n) {
  int i = blockIdx.x * blockDim.x + threadIdx.x;
  if (i < n) hst[i] = 0ull;
}

// ---------------- fp32 -> bf16 convert ----------------
__global__ void k_cvt(const float* __restrict__ in, u16* __restrict__ out, int n) {
  int i = blockIdx.x * blockDim.x + threadIdx.x;
  int stride = gridDim.x * blockDim.x;
  for (; i < n; i += stride) out[i] = f2bf(in[i]);
}

// ---------------- input projection: h = x @ Wp.T + bp ----------------
__global__ __launch_bounds__(512)
void k_proj(const float* __restrict__ x, const float* __restrict__ Wp,
            const float* __restrict__ bp, float* __restrict__ hb) {
  __shared__ float4 xs[128];
  const int tid = threadIdx.x;
  const size_t m0 = (size_t)blockIdx.x * 8;
  if (tid < 128) xs[tid] = ((const float4*)(x + m0 * IN_))[tid];
  __syncthreads();
  float4 wv[16];
  const float4* wp4 = (const float4*)(Wp + (size_t)tid * IN_);
#pragma unroll
  for (int i = 0; i < 16; ++i) wv[i] = wp4[i];
  float acc[8] = {0.f,0.f,0.f,0.f,0.f,0.f,0.f,0.f};
#pragma unroll
  for (int k = 0; k < 16; ++k) {
    float4 w4 = wv[k];
#pragma unroll
    for (int rr = 0; rr < 8; ++rr) {
      float4 xv = xs[rr * 16 + k];
      acc[rr] += w4.x * xv.x + w4.y * xv.y + w4.z * xv.z + w4.w * xv.w;
    }
  }
  float bpv = bp[tid];
#pragma unroll
  for (int rr = 0; rr < 8; ++rr) hb[(m0 + rr) * H_ + tid] = acc[rr] + bpv;
}

// ---------------- LayerNorm (one wave per row) ----------------
__global__ __launch_bounds__(256)
void k_ln(const float* __restrict__ hin, const float* __restrict__ g,
          const float* __restrict__ bta, float* __restrict__ lnout) {
  const int w = threadIdx.x >> 6, lane = threadIdx.x & 63;
  const size_t m = (size_t)blockIdx.x * 4 + w;
  const float4* src = (const float4*)(hin + m * H_);
  float4 a = src[lane * 2], c = src[lane * 2 + 1];
  float sm = a.x + a.y + a.z + a.w + c.x + c.y + c.z + c.w;
  float sq = a.x*a.x + a.y*a.y + a.z*a.z + a.w*a.w + c.x*c.x + c.y*c.y + c.z*c.z + c.w*c.w;
  sm += __shfl_xor(sm, 1);  sq += __shfl_xor(sq, 1);
  sm += __shfl_xor(sm, 2);  sq += __shfl_xor(sq, 2);
  sm += __shfl_xor(sm, 4);  sq += __shfl_xor(sq, 4);
  sm += __shfl_xor(sm, 8);  sq += __shfl_xor(sq, 8);
  sm += __shfl_xor(sm, 16); sq += __shfl_xor(sq, 16);
  sm += __shfl_xor(sm, 32); sq += __shfl_xor(sq, 32);
  float mu = sm * (1.f / 512.f);
  float var = sq * (1.f / 512.f) - mu * mu;
  float inv = 1.f / sqrtf(var + 1e-5f);
  const float4* g4 = (const float4*)g;
  const float4* b4 = (const float4*)bta;
  float4 ga = g4[lane * 2], gc = g4[lane * 2 + 1];
  float4 ba = b4[lane * 2], bc = b4[lane * 2 + 1];
  float4 oa, oc;
  oa.x = (a.x - mu) * inv * ga.x + ba.x;
  oa.y = (a.y - mu) * inv * ga.y + ba.y;
  oa.z = (a.z - mu) * inv * ga.z + ba.z;
  oa.w = (a.w - mu) * inv * ga.w + ba.w;
  oc.x = (c.x - mu) * inv * gc.x + bc.x;
  oc.y = (c.y - mu) * inv * gc.y + bc.y;
  oc.z = (c.z - mu) * inv * gc.z + bc.z;
  oc.w = (c.w - mu) * inv * gc.w + bc.w;
  float4* dst = (float4*)(lnout + m * H_);
  dst[lane * 2] = oa;
  dst[lane * 2 + 1] = oc;
}

// ---------------- fused conv(5,11,23)+BN+GELU+gate softmax+mix ----------------
__global__ __launch_bounds__(512)
void k_mix(const float* __restrict__ ln,
           const float* __restrict__ w0, const float* __restrict__ cb0,
           const float* __restrict__ w1, const float* __restrict__ cb1,
           const float* __restrict__ w2, const float* __restrict__ cb2,
           const float* __restrict__ bng, const float* __restrict__ bnb,
           const float* __restrict__ gW, const float* __restrict__ gb,
           u16* __restrict__ mixbf) {
  const int h = threadIdx.x;
  const int bi = blockIdx.x >> 11;
  const int t = blockIdx.x & (L_ - 1);
  const size_t mrow = (size_t)blockIdx.x;
  float v[23];
#pragma unroll
  for (int d = 0; d < 23; ++d) {
    int tt = t + d - 11;
    v[d] = (tt >= 0 && tt < L_) ? ln[((size_t)bi * L_ + tt) * H_ + h] : 0.f;
  }
  float o0 = cb0[h], o1 = cb1[h], o2 = cb2[h];
#pragma unroll
  for (int d = 0; d < 5; ++d) o0 += v[9 + d] * w0[h * 5 + d];
#pragma unroll
  for (int d = 0; d < 11; ++d) o1 += v[6 + d] * w1[h * 11 + d];
#pragma unroll
  for (int d = 0; d < 23; ++d) o2 += v[d] * w2[h * 23 + d];
  const float bscale = 0.99999500003749968f;  // 1/sqrt(1+1e-5)
  o0 = o0 * (bng[0 * H_ + h] * bscale) + bnb[0 * H_ + h];
  o1 = o1 * (bng[1 * H_ + h] * bscale) + bnb[1 * H_ + h];
  o2 = o2 * (bng[2 * H_ + h] * bscale) + bnb[2 * H_ + h];
  o0 = gelu_exact(o0); o1 = gelu_exact(o1); o2 = gelu_exact(o2);
  float l0 = o0 * gW[0 * H3_ + h] + o1 * gW[0 * H3_ + H_ + h] + o2 * gW[0 * H3_ + 2 * H_ + h];
  float l1 = o0 * gW[1 * H3_ + h] + o1 * gW[1 * H3_ + H_ + h] + o2 * gW[1 * H3_ + 2 * H_ + h];
  float l2 = o0 * gW[2 * H3_ + h] + o1 * gW[2 * H3_ + H_ + h] + o2 * gW[2 * H3_ + 2 * H_ + h];
  l0 += __shfl_xor(l0, 1);  l1 += __shfl_xor(l1, 1);  l2 += __shfl_xor(l2, 1);
  l0 += __shfl_xor(l0, 2);  l1 += __shfl_xor(l1, 2);  l2 += __shfl_xor(l2, 2);
  l0 += __shfl_xor(l0, 4);  l1 += __shfl_xor(l1, 4);  l2 += __shfl_xor(l2, 4);
  l0 += __shfl_xor(l0, 8);  l1 += __shfl_xor(l1, 8);  l2 += __shfl_xor(l2, 8);
  l0 += __shfl_xor(l0, 16); l1 += __shfl_xor(l1, 16); l2 += __shfl_xor(l2, 16);
  l0 += __shfl_xor(l0, 32); l1 += __shfl_xor(l1, 32); l2 += __shfl_xor(l2, 32);
  __shared__ float red[8][3];
  const int w = h >> 6, lane = h & 63;
  if (lane == 0) { red[w][0] = l0; red[w][1] = l1; red[w][2] = l2; }
  __syncthreads();
  l0 = gb[0]; l1 = gb[1]; l2 = gb[2];
#pragma unroll
  for (int i = 0; i < 8; ++i) { l0 += red[i][0]; l1 += red[i][1]; l2 += red[i][2]; }
  float mx = fmaxf(l0, fmaxf(l1, l2));
  float e0 = expf(l0 - mx), e1 = expf(l1 - mx), e2 = expf(l2 - mx);
  float inv = 1.f / (e0 + e1 + e2);
  float out = (o0 * e0 + o1 * e1 + o2 * e2) * inv;
  mixbf[mrow * H_ + h] = f2bf(out);
}

// ---------------- bf16 MFMA GEMM: xg = mixbf @ WihT + bih ----------------
__global__ __launch_bounds__(256)
void k_gemm(const u16* __restrict__ A, const u16* __restrict__ Bm,
            const float* __restrict__ bias, u16* __restrict__ C) {
  __shared__ u16 As[128 * 32];
  __shared__ u16 Bs[128 * 32];
  const int tid = threadIdx.x;
  const int bm = blockIdx.x / 12, bn = blockIdx.x % 12;
  const int m0 = bm * 128, n0 = bn * 128;
  const int w = tid >> 6, lane = tid & 63;
  const int wr = w >> 1, wc = w & 1;
  const int q = lane >> 4, r = lane & 15;
  f32x4 acc[4][4] = {};
  const uint4* Ag = (const uint4*)(A + (size_t)m0 * H_);
  const uint4* Bg = (const uint4*)(Bm + (size_t)n0 * H_);
  uint4* As4 = (uint4*)As;
  uint4* Bs4 = (uint4*)Bs;
  for (int ko = 0; ko < 16; ++ko) {
    __syncthreads();
#pragma unroll
    for (int i = 0; i < 2; ++i) {
      int j = tid + 256 * i;
      As4[j] = Ag[(size_t)(j >> 2) * 64 + (j & 3) + ko * 4];
      Bs4[j] = Bg[(size_t)(j >> 2) * 64 + (j & 3) + ko * 4];
    }
    __syncthreads();
    bf16x8 av[4], bv[4];
#pragma unroll
    for (int m = 0; m < 4; ++m) av[m] = *(const bf16x8*)&As[(wr * 64 + m * 16 + r) * 32 + q * 8];
#pragma unroll
    for (int n = 0; n < 4; ++n) bv[n] = *(const bf16x8*)&Bs[(wc * 64 + n * 16 + r) * 32 + q * 8];
#pragma unroll
    for (int m = 0; m < 4; ++m)
#pragma unroll
      for (int n = 0; n < 4; ++n)
        acc[m][n] = __builtin_amdgcn_mfma_f32_16x16x32_bf16(av[m], bv[n], acc[m][n], 0, 0, 0);
  }
#pragma unroll
  for (int n = 0; n < 4; ++n) {
    int col = n0 + wc * 64 + n * 16 + r;
    float bv_ = bias[col];
#pragma unroll
    for (int m = 0; m < 4; ++m) {
      int row = m0 + wr * 64 + m * 16 + q * 4;
#pragma unroll
      for (int i = 0; i < 4; ++i) {
        float v = acc[m][n][i] + bv_;
        C[(size_t)(row + i) * H3_ + col] = f2bf(v);
      }
    }
  }
}

// ---------------- cooperative GRU scan ----------------
// 256 WGs x 512 threads. wg = s*16+b (keeps a batch's 16 producers on one XCD
// under round-robin dispatch — locality heuristic only, correctness via atomics).
// WG (b,s) owns h-dims [32s,32s+32). Wave w owns dims jj = 4w+g16 (g16=lane>>4);
// thread (jj,l16) holds rows {jj, 512+jj, 1024+jj} x k-slice [32*l16,+32) in VGPRs
// (96 fp32 — no __launch_bounds__ min-occupancy so the allocator keeps them).
// After a 4-hop l16 shuffle reduce, lane l16==0 has r,z,n partials for its dim:
// gates in-register, publish via tagged (value,step) u64 agent atomic; own slice
// written straight to LDS; remote slices polled. One __syncthreads per step.
__global__ __launch_bounds__(512)
void k_gru(const float* __restrict__ Whh_l, const float* __restrict__ bhh_l,
           const u16* __restrict__ xg, const u16* __restrict__ mixbf,
           float* __restrict__ out_h, u64* hst, int tbase) {
  const int tid = threadIdx.x;
  const int wg = blockIdx.x;
  const int b = wg & 15;
  const int s = wg >> 4;
  const int w = tid >> 6;
  const int lane = tid & 63;
  const int g16 = lane >> 4;
  const int l16 = lane & 15;
  const int jj = 4 * w + g16;          // own h-dim within slice (0..31)
  const bool gl = (l16 == 0);         // gate lane for dim jj

  __shared__ __align__(16) float h_s[2][576];  // 16 slices * 36-float padded rows

  float wr_[3][32];
  float bh_[3];
#pragma unroll
  for (int q = 0; q < 3; ++q) {
    const int grow = q * H_ + s * 32 + jj;
    const float4* wp = (const float4*)(Whh_l + (size_t)grow * H_ + l16 * 32);
#pragma unroll
    for (int c = 0; c < 8; ++c) {
      float4 v = wp[c];
      wr_[q][4 * c + 0] = v.x; wr_[q][4 * c + 1] = v.y;
      wr_[q][4 * c + 2] = v.z; wr_[q][4 * c + 3] = v.w;
    }
    bh_[q] = bhh_l[grow];
  }

  h_s[0][(tid >> 5) * 36 + (tid & 31)] = 0.f;  // h_{-1} = 0
  float hp = 0.f;                               // gate lane: own previous h
  __syncthreads();

  const int PSTRIDE = B_ * H_;
  const bool remote = ((tid >> 5) != s);        // poll only non-own slices

  for (int t = 0; t < L_; ++t) {
    // gate-lane prefetch of xg/mix for this t (lands under the matvec)
    u16 xr_u = 0, xz_u = 0, xn_u = 0, mx_u = 0;
    size_t orow = ((size_t)b * L_ + t) * H_ + s * 32 + jj;
    if (gl) {
      size_t xb = ((size_t)b * L_ + t) * H3_ + s * 32 + jj;
      xr_u = xg[xb];
      xz_u = xg[xb + H_];
      xn_u = xg[xb + 2 * H_];
      mx_u = mixbf[orow];
    }
    // matvec partials: 3 gate rows, 32 k each
    float p0 = 0.f, p1 = 0.f, p2 = 0.f;
    const float* hrow = &h_s[t & 1][l16 * 36];
#pragma unroll
    for (int c = 0; c < 8; ++c) {
      float4 hv = *(const float4*)(hrow + c * 4);
      p0 += wr_[0][4*c]*hv.x + wr_[0][4*c+1]*hv.y + wr_[0][4*c+2]*hv.z + wr_[0][4*c+3]*hv.w;
      p1 += wr_[1][4*c]*hv.x + wr_[1][4*c+1]*hv.y + wr_[1][4*c+2]*hv.z + wr_[1][4*c+3]*hv.w;
      p2 += wr_[2][4*c]*hv.x + wr_[2][4*c+1]*hv.y + wr_[2][4*c+2]*hv.z + wr_[2][4*c+3]*hv.w;
    }
    p0 += __shfl_xor(p0, 1); p1 += __shfl_xor(p1, 1); p2 += __shfl_xor(p2, 1);
    p0 += __shfl_xor(p0, 2); p1 += __shfl_xor(p1, 2); p2 += __shfl_xor(p2, 2);
    p0 += __shfl_xor(p0, 4); p1 += __shfl_xor(p1, 4); p2 += __shfl_xor(p2, 4);
    p0 += __shfl_xor(p0, 8); p1 += __shfl_xor(p1, 8); p2 += __shfl_xor(p2, 8);

    if (gl) {
      float r = fast_sig(bf2f(xr_u) + p0 + bh_[0]);
      float z = fast_sig(bf2f(xz_u) + p1 + bh_[1]);
      float n = fast_tanh(bf2f(xn_u) + r * (p2 + bh_[2]));
      float hnew = n + z * (hp - n);
      hp = hnew;
      out_h[orow] = bf2f(mx_u) + hnew;
      h_s[(t + 1) & 1][s * 36 + jj] = hnew;   // own slice: straight to LDS
      if (t + 1 < L_) {
        u64 pv = ((u64)(unsigned)(tbase + t + 1) << 32) | (u64)__float_as_uint(hnew);
        __hip_atomic_store(&hst[(size_t)((t + 1) & 1) * PSTRIDE + (size_t)b * H_ + s * 32 + jj],
                           pv, __ATOMIC_RELAXED, __HIP_MEMORY_SCOPE_AGENT);
      }
    }

    if (remote && t + 1 < L_) {
      const unsigned T = (unsigned)(tbase + t + 1);
      u64* sl = &hst[(size_t)((t + 1) & 1) * PSTRIDE + (size_t)b * H_ + tid];
      u64 v;
      do {
        v = __hip_atomic_load(sl, __ATOMIC_RELAXED, __HIP_MEMORY_SCOPE_AGENT);
      } while ((unsigned)(v >> 32) != T);
      h_s[(t + 1) & 1][(tid >> 5) * 36 + (tid & 31)] = __uint_as_float((unsigned)v);
    }
    __syncthreads();
  }
}

extern "C" void kernel_launch(void* const* d_in, const int* in_sizes, int n_in,
                              void* d_out, int out_size, void* d_ws, size_t ws_size,
                              hipStream_t stream) {
  (void)in_sizes; (void)n_in; (void)out_size; (void)ws_size;
  const float* x    = (const float*)d_in[0];
  const float* Wp   = (const float*)d_in[1];
  const float* bp   = (const float*)d_in[2];
  const float* ln_g = (const float*)d_in[3];
  const float* ln_b = (const float*)d_in[4];
  const float* cw0  = (const float*)d_in[5];
  const float* cb0  = (const float*)d_in[6];
  const float* cw1  = (const float*)d_in[7];
  const float* cb1  = (const float*)d_in[8];
  const float* cw2  = (const float*)d_in[9];
  const float* cb2  = (const float*)d_in[10];
  const float* bng  = (const float*)d_in[11];
  const float* bnb  = (const float*)d_in[12];
  const float* gW   = (const float*)d_in[13];
  const float* gb   = (const float*)d_in[14];
  const float* Wih  = (const float*)d_in[15];
  const float* Whh  = (const float*)d_in[16];
  const float* bih  = (const float*)d_in[17];
  const float* bhh  = (const float*)d_in[18];

  char* ws = (char*)d_ws;
  u16*   xg    = (u16*)(ws + 0);
  float* ln    = (float*)(ws + 0);  // alias: consumed (by k_mix) before k_gemm writes xg
  u16*   mixbf = (u16*)(ws + (size_t)96 * 1024 * 1024);
  u16*   wihbf = (u16*)(ws + (size_t)128 * 1024 * 1024);
  u64*   hst   = (u64*)(ws + (size_t)134 * 1024 * 1024);
  float* hbuf  = (float*)d_out;     // inter-layer h lives in d_out

  k_init<<<dim3(64), dim3(256), 0, stream>>>(hst, 2 * B_ * H_);
  k_cvt<<<dim3(3072), dim3(256), 0, stream>>>(Wih, wihbf, NL_ * H3_ * H_);
  k_proj<<<dim3(B_ * L_ / 8), dim3(512), 0, stream>>>(x, Wp, bp, hbuf);

  for (int l = 0; l < NL_; ++l) {
    k_ln<<<dim3(B_ * L_ / 4), dim3(256), 0, stream>>>(hbuf, ln_g + l * H_, ln_b + l * H_, ln);
    k_mix<<<dim3(B_ * L_), dim3(512), 0, stream>>>(ln,
        cw0 + l * H_ * 5,  cb0 + l * H_,
        cw1 + l * H_ * 11, cb1 + l * H_,
        cw2 + l * H_ * 23, cb2 + l * H_,
        bng + l * 3 * H_, bnb + l * 3 * H_,
        gW + l * 3 * H3_, gb + l * 3, mixbf);
    k_gemm<<<dim3((B_ * L_ / 128) * (H3_ / 128)), dim3(256), 0, stream>>>(
        mixbf, wihbf + (size_t)l * H3_ * H_, bih + l * H3_, xg);

    const float* whh_l = Whh + (size_t)l * H3_ * H_;
    const float* bhh_l = bhh + l * H3_;
    const u16* xg_c = xg;
    const u16* mix_c = mixbf;
    float* outp = hbuf;
    int tbase = l * L_;
    void* args[] = { (void*)&whh_l, (void*)&bhh_l, (void*)&xg_c, (void*)&mix_c,
                     (void*)&outp, (void*)&hst, (void*)&tbase };
    hipLaunchCooperativeKernel((void*)k_gru, dim3(B_ * 16), dim3(512), args, 0, stream);
  }
}

// Round 4
// 19861.192 us; speedup vs baseline: 1.5151x; 1.5151x over previous
//
#include <hip/hip_runtime.h>
#include <hip/hip_bf16.h>

// xLSTMStack: proj -> 4x( LN -> conv-mix -> bf16 MFMA GEMM (xg) -> cooperative GRU scan + residual )
// Workspace layout (~134.2 MiB):
//   [0,96M)     xg bf16 [B*L*3H]   (first 64 MiB aliased as ln fp32, consumed before xg written)
//   [96,128M)   mixbf bf16 [B*L*H] (GEMM A input + residual source for GRU)
//   [128,134M)  Wih bf16 [4*3H*H]
//   [134M,+128K) hst u64 [2][B][H] tagged (value,step) h-state
// d_out (fp32 [B,L,H]) doubles as the inter-layer h buffer.

#define B_   16
#define L_   2048
#define IN_  64
#define H_   512
#define H3_  1536
#define NL_  4

typedef unsigned short u16;
typedef unsigned long long u64;
typedef short bf16x8 __attribute__((ext_vector_type(8)));
typedef float f32x4 __attribute__((ext_vector_type(4)));

__device__ __forceinline__ u16 f2bf(float f) {
  unsigned u = __float_as_uint(f);
  u = u + 0x7fffu + ((u >> 16) & 1u);
  return (u16)(u >> 16);
}
__device__ __forceinline__ float bf2f(u16 v) {
  return __uint_as_float(((unsigned)v) << 16);
}
__device__ __forceinline__ float gelu_exact(float x) {
  return 0.5f * x * (1.f + erff(x * 0.70710678118654752440f));
}
__device__ __forceinline__ float fast_sig(float x) {
  float e = __expf(-x);
  return __builtin_amdgcn_rcpf(1.f + e);
}
__device__ __forceinline__ float fast_tanh(float x) {
  x = fminf(fmaxf(x, -15.f), 15.f);
  float e = __expf(2.f * x);
  return (e - 1.f) * __builtin_amdgcn_rcpf(e + 1.f);
}
__device__ __forceinline__ float dot4(float4 a, float4 b) {
  return a.x * b.x + a.y * b.y + a.z * b.z + a.w * b.w;
}

// ---------------- init: zero tagged h-state ----------------
__global__ void k_init(u64* hst, int n) {
  int i = blockIdx.x * blockDim.x + threadIdx.x;
  if (i < n) hst[i] = 0ull;
}

// ---------------- fp32 -> bf16 convert ----------------
__global__ void k_cvt(const float* __restrict__ in, u16* __restrict__ out, int n) {
  int i = blockIdx.x * blockDim.x + threadIdx.x;
  int stride = gridDim.x * blockDim.x;
  for (; i < n; i += stride) out[i] = f2bf(in[i]);
}

// ---------------- input projection: h = x @ Wp.T + bp ----------------
__global__ __launch_bounds__(512)
void k_proj(const float* __restrict__ x, const float* __restrict__ Wp,
            const float* __restrict__ bp, float* __restrict__ hb) {
  __shared__ float4 xs[128];
  const int tid = threadIdx.x;
  const size_t m0 = (size_t)blockIdx.x * 8;
  if (tid < 128) xs[tid] = ((const float4*)(x + m0 * IN_))[tid];
  __syncthreads();
  float4 wv[16];
  const float4* wp4 = (const float4*)(Wp + (size_t)tid * IN_);
#pragma unroll
  for (int i = 0; i < 16; ++i) wv[i] = wp4[i];
  float acc[8] = {0.f,0.f,0.f,0.f,0.f,0.f,0.f,0.f};
#pragma unroll
  for (int k = 0; k < 16; ++k) {
    float4 w4 = wv[k];
#pragma unroll
    for (int rr = 0; rr < 8; ++rr) {
      float4 xv = xs[rr * 16 + k];
      acc[rr] += w4.x * xv.x + w4.y * xv.y + w4.z * xv.z + w4.w * xv.w;
    }
  }
  float bpv = bp[tid];
#pragma unroll
  for (int rr = 0; rr < 8; ++rr) hb[(m0 + rr) * H_ + tid] = acc[rr] + bpv;
}

// ---------------- LayerNorm (one wave per row) ----------------
__global__ __launch_bounds__(256)
void k_ln(const float* __restrict__ hin, const float* __restrict__ g,
          const float* __restrict__ bta, float* __restrict__ lnout) {
  const int w = threadIdx.x >> 6, lane = threadIdx.x & 63;
  const size_t m = (size_t)blockIdx.x * 4 + w;
  const float4* src = (const float4*)(hin + m * H_);
  float4 a = src[lane * 2], c = src[lane * 2 + 1];
  float sm = a.x + a.y + a.z + a.w + c.x + c.y + c.z + c.w;
  float sq = a.x*a.x + a.y*a.y + a.z*a.z + a.w*a.w + c.x*c.x + c.y*c.y + c.z*c.z + c.w*c.w;
  sm += __shfl_xor(sm, 1);  sq += __shfl_xor(sq, 1);
  sm += __shfl_xor(sm, 2);  sq += __shfl_xor(sq, 2);
  sm += __shfl_xor(sm, 4);  sq += __shfl_xor(sq, 4);
  sm += __shfl_xor(sm, 8);  sq += __shfl_xor(sq, 8);
  sm += __shfl_xor(sm, 16); sq += __shfl_xor(sq, 16);
  sm += __shfl_xor(sm, 32); sq += __shfl_xor(sq, 32);
  float mu = sm * (1.f / 512.f);
  float var = sq * (1.f / 512.f) - mu * mu;
  float inv = 1.f / sqrtf(var + 1e-5f);
  const float4* g4 = (const float4*)g;
  const float4* b4 = (const float4*)bta;
  float4 ga = g4[lane * 2], gc = g4[lane * 2 + 1];
  float4 ba = b4[lane * 2], bc = b4[lane * 2 + 1];
  float4 oa, oc;
  oa.x = (a.x - mu) * inv * ga.x + ba.x;
  oa.y = (a.y - mu) * inv * ga.y + ba.y;
  oa.z = (a.z - mu) * inv * ga.z + ba.z;
  oa.w = (a.w - mu) * inv * ga.w + ba.w;
  oc.x = (c.x - mu) * inv * gc.x + bc.x;
  oc.y = (c.y - mu) * inv * gc.y + bc.y;
  oc.z = (c.z - mu) * inv * gc.z + bc.z;
  oc.w = (c.w - mu) * inv * gc.w + bc.w;
  float4* dst = (float4*)(lnout + m * H_);
  dst[lane * 2] = oa;
  dst[lane * 2 + 1] = oc;
}

// ---------------- fused conv(5,11,23)+BN+GELU+gate softmax+mix ----------------
__global__ __launch_bounds__(512)
void k_mix(const float* __restrict__ ln,
           const float* __restrict__ w0, const float* __restrict__ cb0,
           const float* __restrict__ w1, const float* __restrict__ cb1,
           const float* __restrict__ w2, const float* __restrict__ cb2,
           const float* __restrict__ bng, const float* __restrict__ bnb,
           const float* __restrict__ gW, const float* __restrict__ gb,
           u16* __restrict__ mixbf) {
  const int h = threadIdx.x;
  const int bi = blockIdx.x >> 11;
  const int t = blockIdx.x & (L_ - 1);
  const size_t mrow = (size_t)blockIdx.x;
  float v[23];
#pragma unroll
  for (int d = 0; d < 23; ++d) {
    int tt = t + d - 11;
    v[d] = (tt >= 0 && tt < L_) ? ln[((size_t)bi * L_ + tt) * H_ + h] : 0.f;
  }
  float o0 = cb0[h], o1 = cb1[h], o2 = cb2[h];
#pragma unroll
  for (int d = 0; d < 5; ++d) o0 += v[9 + d] * w0[h * 5 + d];
#pragma unroll
  for (int d = 0; d < 11; ++d) o1 += v[6 + d] * w1[h * 11 + d];
#pragma unroll
  for (int d = 0; d < 23; ++d) o2 += v[d] * w2[h * 23 + d];
  const float bscale = 0.99999500003749968f;  // 1/sqrt(1+1e-5)
  o0 = o0 * (bng[0 * H_ + h] * bscale) + bnb[0 * H_ + h];
  o1 = o1 * (bng[1 * H_ + h] * bscale) + bnb[1 * H_ + h];
  o2 = o2 * (bng[2 * H_ + h] * bscale) + bnb[2 * H_ + h];
  o0 = gelu_exact(o0); o1 = gelu_exact(o1); o2 = gelu_exact(o2);
  float l0 = o0 * gW[0 * H3_ + h] + o1 * gW[0 * H3_ + H_ + h] + o2 * gW[0 * H3_ + 2 * H_ + h];
  float l1 = o0 * gW[1 * H3_ + h] + o1 * gW[1 * H3_ + H_ + h] + o2 * gW[1 * H3_ + 2 * H_ + h];
  float l2 = o0 * gW[2 * H3_ + h] + o1 * gW[2 * H3_ + H_ + h] + o2 * gW[2 * H3_ + 2 * H_ + h];
  l0 += __shfl_xor(l0, 1);  l1 += __shfl_xor(l1, 1);  l2 += __shfl_xor(l2, 1);
  l0 += __shfl_xor(l0, 2);  l1 += __shfl_xor(l1, 2);  l2 += __shfl_xor(l2, 2);
  l0 += __shfl_xor(l0, 4);  l1 += __shfl_xor(l1, 4);  l2 += __shfl_xor(l2, 4);
  l0 += __shfl_xor(l0, 8);  l1 += __shfl_xor(l1, 8);  l2 += __shfl_xor(l2, 8);
  l0 += __shfl_xor(l0, 16); l1 += __shfl_xor(l1, 16); l2 += __shfl_xor(l2, 16);
  l0 += __shfl_xor(l0, 32); l1 += __shfl_xor(l1, 32); l2 += __shfl_xor(l2, 32);
  __shared__ float red[8][3];
  const int w = h >> 6, lane = h & 63;
  if (lane == 0) { red[w][0] = l0; red[w][1] = l1; red[w][2] = l2; }
  __syncthreads();
  l0 = gb[0]; l1 = gb[1]; l2 = gb[2];
#pragma unroll
  for (int i = 0; i < 8; ++i) { l0 += red[i][0]; l1 += red[i][1]; l2 += red[i][2]; }
  float mx = fmaxf(l0, fmaxf(l1, l2));
  float e0 = expf(l0 - mx), e1 = expf(l1 - mx), e2 = expf(l2 - mx);
  float inv = 1.f / (e0 + e1 + e2);
  float out = (o0 * e0 + o1 * e1 + o2 * e2) * inv;
  mixbf[mrow * H_ + h] = f2bf(out);
}

// ---------------- bf16 MFMA GEMM: xg = mixbf @ WihT + bih ----------------
__global__ __launch_bounds__(256)
void k_gemm(const u16* __restrict__ A, const u16* __restrict__ Bm,
            const float* __restrict__ bias, u16* __restrict__ C) {
  __shared__ u16 As[128 * 32];
  __shared__ u16 Bs[128 * 32];
  const int tid = threadIdx.x;
  const int bm = blockIdx.x / 12, bn = blockIdx.x % 12;
  const int m0 = bm * 128, n0 = bn * 128;
  const int w = tid >> 6, lane = tid & 63;
  const int wr = w >> 1, wc = w & 1;
  const int q = lane >> 4, r = lane & 15;
  f32x4 acc[4][4] = {};
  const uint4* Ag = (const uint4*)(A + (size_t)m0 * H_);
  const uint4* Bg = (const uint4*)(Bm + (size_t)n0 * H_);
  uint4* As4 = (uint4*)As;
  uint4* Bs4 = (uint4*)Bs;
  for (int ko = 0; ko < 16; ++ko) {
    __syncthreads();
#pragma unroll
    for (int i = 0; i < 2; ++i) {
      int j = tid + 256 * i;
      As4[j] = Ag[(size_t)(j >> 2) * 64 + (j & 3) + ko * 4];
      Bs4[j] = Bg[(size_t)(j >> 2) * 64 + (j & 3) + ko * 4];
    }
    __syncthreads();
    bf16x8 av[4], bv[4];
#pragma unroll
    for (int m = 0; m < 4; ++m) av[m] = *(const bf16x8*)&As[(wr * 64 + m * 16 + r) * 32 + q * 8];
#pragma unroll
    for (int n = 0; n < 4; ++n) bv[n] = *(const bf16x8*)&Bs[(wc * 64 + n * 16 + r) * 32 + q * 8];
#pragma unroll
    for (int m = 0; m < 4; ++m)
#pragma unroll
      for (int n = 0; n < 4; ++n)
        acc[m][n] = __builtin_amdgcn_mfma_f32_16x16x32_bf16(av[m], bv[n], acc[m][n], 0, 0, 0);
  }
#pragma unroll
  for (int n = 0; n < 4; ++n) {
    int col = n0 + wc * 64 + n * 16 + r;
    float bv_ = bias[col];
#pragma unroll
    for (int m = 0; m < 4; ++m) {
      int row = m0 + wr * 64 + m * 16 + q * 4;
#pragma unroll
      for (int i = 0; i < 4; ++i) {
        float v = acc[m][n][i] + bv_;
        C[(size_t)(row + i) * H3_ + col] = f2bf(v);
      }
    }
  }
}

// ---------------- cooperative GRU scan ----------------
// 256 WGs x 512 threads, wg = b*16+s (natural mapping: spreads each batch's
// producers/pollers across XCDs and L3 channels — s*16+b hotspotted L3).
// WG (b,s) owns h-dims [32s,32s+32). Wave w owns dims jj = 4w+g16; thread
// (jj,l16) holds rows {jj,512+jj,1024+jj} x k-slice [32*l16,+32) as 24 NAMED
// float4s (defeats array->scratch demotion; round-3 VGPR=72 proved arrays spill).
// 4-hop shuffle reduce -> lane l16==0 owns dim jj: gates in-register, publish
// tagged (value,step) u64 agent atomic, own slice straight to LDS, remote
// slices polled. One __syncthreads per step.
__global__ __launch_bounds__(512, 1)
void k_gru(const float* __restrict__ Whh_l, const float* __restrict__ bhh_l,
           const u16* __restrict__ xg, const u16* __restrict__ mixbf,
           float* __restrict__ out_h, u64* hst, int tbase) {
  const int tid = threadIdx.x;
  const int wg = blockIdx.x;
  const int b = wg >> 4;
  const int s = wg & 15;
  const int w = tid >> 6;
  const int lane = tid & 63;
  const int g16 = lane >> 4;
  const int l16 = lane & 15;
  const int jj = 4 * w + g16;          // own h-dim within slice (0..31)
  const bool gl = (l16 == 0);          // gate lane for dim jj

  __shared__ __align__(16) float h_s[2][576];  // 16 slices * 36-float padded rows

  const float4* Wr4 = (const float4*)(Whh_l + (size_t)(0 * H_ + s * 32 + jj) * H_ + l16 * 32);
  const float4* Wz4 = (const float4*)(Whh_l + (size_t)(1 * H_ + s * 32 + jj) * H_ + l16 * 32);
  const float4* Wn4 = (const float4*)(Whh_l + (size_t)(2 * H_ + s * 32 + jj) * H_ + l16 * 32);
  float4 wr0 = Wr4[0], wr1 = Wr4[1], wr2 = Wr4[2], wr3 = Wr4[3],
         wr4 = Wr4[4], wr5 = Wr4[5], wr6 = Wr4[6], wr7 = Wr4[7];
  float4 wz0 = Wz4[0], wz1 = Wz4[1], wz2 = Wz4[2], wz3 = Wz4[3],
         wz4 = Wz4[4], wz5 = Wz4[5], wz6 = Wz4[6], wz7 = Wz4[7];
  float4 wn0 = Wn4[0], wn1 = Wn4[1], wn2 = Wn4[2], wn3 = Wn4[3],
         wn4 = Wn4[4], wn5 = Wn4[5], wn6 = Wn4[6], wn7 = Wn4[7];
  const float br_ = bhh_l[0 * H_ + s * 32 + jj];
  const float bz_ = bhh_l[1 * H_ + s * 32 + jj];
  const float bn_ = bhh_l[2 * H_ + s * 32 + jj];

  h_s[0][(tid >> 5) * 36 + (tid & 31)] = 0.f;  // h_{-1} = 0
  float hp = 0.f;                               // gate lane: own previous h
  __syncthreads();

  const int PSTRIDE = B_ * H_;
  const bool remote = ((tid >> 5) != s);        // poll only non-own slices

  for (int t = 0; t < L_; ++t) {
    // gate-lane prefetch of xg/mix for this t (lands under the matvec)
    u16 xr_u = 0, xz_u = 0, xn_u = 0, mx_u = 0;
    size_t orow = ((size_t)b * L_ + t) * H_ + s * 32 + jj;
    if (gl) {
      size_t xb = ((size_t)b * L_ + t) * H3_ + s * 32 + jj;
      xr_u = xg[xb];
      xz_u = xg[xb + H_];
      xn_u = xg[xb + 2 * H_];
      mx_u = mixbf[orow];
    }
    // matvec partials: 3 gate rows x 32 k, all operands in VGPRs
    const float4* hq = (const float4*)(&h_s[t & 1][l16 * 36]);
    float4 h0 = hq[0], h1 = hq[1], h2 = hq[2], h3 = hq[3],
           h4 = hq[4], h5 = hq[5], h6 = hq[6], h7 = hq[7];
    float p0 = dot4(wr0, h0) + dot4(wr1, h1) + dot4(wr2, h2) + dot4(wr3, h3)
             + dot4(wr4, h4) + dot4(wr5, h5) + dot4(wr6, h6) + dot4(wr7, h7);
    float p1 = dot4(wz0, h0) + dot4(wz1, h1) + dot4(wz2, h2) + dot4(wz3, h3)
             + dot4(wz4, h4) + dot4(wz5, h5) + dot4(wz6, h6) + dot4(wz7, h7);
    float p2 = dot4(wn0, h0) + dot4(wn1, h1) + dot4(wn2, h2) + dot4(wn3, h3)
             + dot4(wn4, h4) + dot4(wn5, h5) + dot4(wn6, h6) + dot4(wn7, h7);
    p0 += __shfl_xor(p0, 1); p1 += __shfl_xor(p1, 1); p2 += __shfl_xor(p2, 1);
    p0 += __shfl_xor(p0, 2); p1 += __shfl_xor(p1, 2); p2 += __shfl_xor(p2, 2);
    p0 += __shfl_xor(p0, 4); p1 += __shfl_xor(p1, 4); p2 += __shfl_xor(p2, 4);
    p0 += __shfl_xor(p0, 8); p1 += __shfl_xor(p1, 8); p2 += __shfl_xor(p2, 8);

    if (gl) {
      float r = fast_sig(bf2f(xr_u) + p0 + br_);
      float z = fast_sig(bf2f(xz_u) + p1 + bz_);
      float n = fast_tanh(bf2f(xn_u) + r * (p2 + bn_));
      float hnew = n + z * (hp - n);
      hp = hnew;
      if (t + 1 < L_) {   // publish first: it's on the other WGs' critical path
        u64 pv = ((u64)(unsigned)(tbase + t + 1) << 32) | (u64)__float_as_uint(hnew);
        __hip_atomic_store(&hst[(size_t)((t + 1) & 1) * PSTRIDE + (size_t)b * H_ + s * 32 + jj],
                           pv, __ATOMIC_RELAXED, __HIP_MEMORY_SCOPE_AGENT);
      }
      h_s[(t + 1) & 1][s * 36 + jj] = hnew;   // own slice: straight to LDS
      out_h[orow] = bf2f(mx_u) + hnew;
    }

    if (remote && t + 1 < L_) {
      const unsigned T = (unsigned)(tbase + t + 1);
      u64* sl = &hst[(size_t)((t + 1) & 1) * PSTRIDE + (size_t)b * H_ + tid];
      u64 v;
      do {
        v = __hip_atomic_load(sl, __ATOMIC_RELAXED, __HIP_MEMORY_SCOPE_AGENT);
      } while ((unsigned)(v >> 32) != T);
      h_s[(t + 1) & 1][(tid >> 5) * 36 + (tid & 31)] = __uint_as_float((unsigned)v);
    }
    __syncthreads();
  }
}

extern "C" void kernel_launch(void* const* d_in, const int* in_sizes, int n_in,
                              void* d_out, int out_size, void* d_ws, size_t ws_size,
                              hipStream_t stream) {
  (void)in_sizes; (void)n_in; (void)out_size; (void)ws_size;
  const float* x    = (const float*)d_in[0];
  const float* Wp   = (const float*)d_in[1];
  const float* bp   = (const float*)d_in[2];
  const float* ln_g = (const float*)d_in[3];
  const float* ln_b = (const float*)d_in[4];
  const float* cw0  = (const float*)d_in[5];
  const float* cb0  = (const float*)d_in[6];
  const float* cw1  = (const float*)d_in[7];
  const float* cb1  = (const float*)d_in[8];
  const float* cw2  = (const float*)d_in[9];
  const float* cb2  = (const float*)d_in[10];
  const float* bng  = (const float*)d_in[11];
  const float* bnb  = (const float*)d_in[12];
  const float* gW   = (const float*)d_in[13];
  const float* gb   = (const float*)d_in[14];
  const float* Wih  = (const float*)d_in[15];
  const float* Whh  = (const float*)d_in[16];
  const float* bih  = (const float*)d_in[17];
  const float* bhh  = (const float*)d_in[18];

  char* ws = (char*)d_ws;
  u16*   xg    = (u16*)(ws + 0);
  float* ln    = (float*)(ws + 0);  // alias: consumed (by k_mix) before k_gemm writes xg
  u16*   mixbf = (u16*)(ws + (size_t)96 * 1024 * 1024);
  u16*   wihbf = (u16*)(ws + (size_t)128 * 1024 * 1024);
  u64*   hst   = (u64*)(ws + (size_t)134 * 1024 * 1024);
  float* hbuf  = (float*)d_out;     // inter-layer h lives in d_out

  k_init<<<dim3(64), dim3(256), 0, stream>>>(hst, 2 * B_ * H_);
  k_cvt<<<dim3(3072), dim3(256), 0, stream>>>(Wih, wihbf, NL_ * H3_ * H_);
  k_proj<<<dim3(B_ * L_ / 8), dim3(512), 0, stream>>>(x, Wp, bp, hbuf);

  for (int l = 0; l < NL_; ++l) {
    k_ln<<<dim3(B_ * L_ / 4), dim3(256), 0, stream>>>(hbuf, ln_g + l * H_, ln_b + l * H_, ln);
    k_mix<<<dim3(B_ * L_), dim3(512), 0, stream>>>(ln,
        cw0 + l * H_ * 5,  cb0 + l * H_,
        cw1 + l * H_ * 11, cb1 + l * H_,
        cw2 + l * H_ * 23, cb2 + l * H_,
        bng + l * 3 * H_, bnb + l * 3 * H_,
        gW + l * 3 * H3_, gb + l * 3, mixbf);
    k_gemm<<<dim3((B_ * L_ / 128) * (H3_ / 128)), dim3(256), 0, stream>>>(
        mixbf, wihbf + (size_t)l * H3_ * H_, bih + l * H3_, xg);

    const float* whh_l = Whh + (size_t)l * H3_ * H_;
    const float* bhh_l = bhh + l * H3_;
    const u16* xg_c = xg;
    const u16* mix_c = mixbf;
    float* outp = hbuf;
    int tbase = l * L_;
    void* args[] = { (void*)&whh_l, (void*)&bhh_l, (void*)&xg_c, (void*)&mix_c,
                     (void*)&outp, (void*)&hst, (void*)&tbase };
    hipLaunchCooperativeKernel((void*)k_gru, dim3(B_ * 16), dim3(512), args, 0, stream);
  }
}